// Round 7
// baseline (175.696 us; speedup 1.0000x reference)
//
#include <hip/hip_runtime.h>
#include <math.h>

#define CC 128      // channels (FIN=HID=OUT)
#define TPAD 132    // LDS transpose row stride (u16): 264B, 8B-aligned, 2-way-free banks

typedef unsigned short u16;
typedef short bf16x8 __attribute__((ext_vector_type(8)));
typedef short bf16x4 __attribute__((ext_vector_type(4)));
typedef float f32x4 __attribute__((ext_vector_type(4)));

__device__ __forceinline__ u16 f2bf(float f) {
    union { float f; unsigned u; } v; v.f = f;
    unsigned u = v.u;
    return (u16)((u + 0x7FFFu + ((u >> 16) & 1u)) >> 16);   // RNE
}
__device__ __forceinline__ float bf2f(unsigned hi16) {
    union { unsigned u; float f; } v; v.u = hi16 << 16; return v.f;
}

// Exact-GELU via branch-free A&S 7.1.26 erf (|err| < 1.5e-7, far below bf16 noise).
__device__ __forceinline__ float gelu_f(float y) {
    float xa = fabsf(y) * 0.70710678118654752f;
    float t  = __builtin_amdgcn_rcpf(fmaf(0.3275911f, xa, 1.0f));
    float p  = fmaf(1.061405429f, t, -1.453152027f);
    p = fmaf(p, t, 1.421413741f);
    p = fmaf(p, t, -0.284496736f);
    p = fmaf(p, t, 0.254829592f);
    p *= t;
    float e  = __expf(-xa * xa);
    float er = fmaf(-p, e, 1.0f);          // erf(|x|)
    float s  = copysignf(er, y);
    return 0.5f * y * (1.0f + s);
}

// ---------------- CSR build ----------------

__global__ __launch_bounds__(256) void k_zero_i32(int* __restrict__ p, int n) {
    int i = blockIdx.x * 256 + threadIdx.x;
    if (i < n) p[i] = 0;
}

__global__ __launch_bounds__(256) void k_hist(const int* __restrict__ row, int* __restrict__ cnt, int E) {
    int e = blockIdx.x * 256 + threadIdx.x;
    if (e < E) atomicAdd(&cnt[row[e]], 1);
}

__device__ __forceinline__ int wave_incl_scan(int v) {
    #pragma unroll
    for (int d = 1; d < 64; d <<= 1) {
        int t = __shfl_up(v, d);
        if ((threadIdx.x & 63) >= d) v += t;
    }
    return v;
}

__global__ __launch_bounds__(256) void k_scan_a(const int* __restrict__ cnt, int* __restrict__ bsum, int N) {
    int base = blockIdx.x * 1024 + threadIdx.x * 4;
    int s = 0;
    #pragma unroll
    for (int u = 0; u < 4; ++u) { int i = base + u; if (i < N) s += cnt[i]; }
    #pragma unroll
    for (int d = 32; d > 0; d >>= 1) s += __shfl_down(s, d);
    __shared__ int wsum[4];
    if ((threadIdx.x & 63) == 0) wsum[threadIdx.x >> 6] = s;
    __syncthreads();
    if (threadIdx.x == 0) bsum[blockIdx.x] = wsum[0] + wsum[1] + wsum[2] + wsum[3];
}

__global__ __launch_bounds__(64) void k_scan_b(const int* __restrict__ bsum, int* __restrict__ boff,
                                               int* __restrict__ off, int N, int nb) {
    int carry = 0;
    for (int base = 0; base < nb; base += 64) {
        int t = base + (int)threadIdx.x;
        int v = (t < nb) ? bsum[t] : 0;
        int incl = wave_incl_scan(v);
        if (t < nb) boff[t] = carry + incl - v;
        carry += __shfl(incl, 63);
    }
    if (threadIdx.x == 0) off[N] = carry;
}

// local scan + global offset -> off[i]; also zeroes cnt for the subsequent k_fill
__global__ __launch_bounds__(256) void k_scan_c(int* __restrict__ cnt, const int* __restrict__ boff,
                                                int* __restrict__ off, int N) {
    int t = threadIdx.x;
    int base = blockIdx.x * 1024 + t * 4;
    int v[4]; int s = 0;
    #pragma unroll
    for (int u = 0; u < 4; ++u) { int i = base + u; v[u] = (i < N) ? cnt[i] : 0; s += v[u]; }
    int incl = wave_incl_scan(s);
    __shared__ int wsum[4];
    int w = t >> 6, lane = t & 63;
    if (lane == 63) wsum[w] = incl;
    __syncthreads();
    int run = incl - s + boff[blockIdx.x];
    for (int ww = 0; ww < w; ++ww) run += wsum[ww];
    #pragma unroll
    for (int u = 0; u < 4; ++u) {
        int i = base + u;
        if (i < N) { off[i] = run; cnt[i] = 0; }
        run += v[u];
    }
}

// packed edge list: .x = src col, .y = weight bits
__global__ __launch_bounds__(256) void k_fill(const int* __restrict__ row, const int* __restrict__ col,
                                              const float* __restrict__ nrm, const int* __restrict__ off,
                                              int* __restrict__ cur, int2* __restrict__ eg, int E) {
    int e = blockIdx.x * 256 + threadIdx.x;
    if (e < E) {
        int r = row[e];
        int p = off[r] + atomicAdd(&cur[r], 1);
        eg[p] = make_int2(col[e], __float_as_int(nrm[e]));
    }
}

// ---------------- W1,W2 -> bf16, repacked into MFMA B-fragment order ----------------
// Wp[((t*4+s)*64 + l)*8 + j] = bf16( W[16t + (l&15)][s*32 + (l>>4)*8 + j] )
__global__ __launch_bounds__(256) void k_wrepack(const float* __restrict__ W1, u16* __restrict__ Wp1,
                                                 const float* __restrict__ W2, u16* __restrict__ Wp2) {
    int i = blockIdx.x * 256 + threadIdx.x;
    const float* W = (i < CC * CC) ? W1 : W2;
    u16* Wp = (i < CC * CC) ? Wp1 : Wp2;
    int ii = (i < CC * CC) ? i : i - CC * CC;
    if (ii < CC * CC) {
        int j = ii & 7, l = (ii >> 3) & 63, s = (ii >> 9) & 3, t = ii >> 11;
        int r = 16 * t + (l & 15);
        int k = s * 32 + (l >> 4) * 8 + j;
        Wp[ii] = f2bf(W[r * CC + k]);
    }
}

// ---------------- fused MFMA GEMM + BatchNorm + GELU (pinned register-resident B) ----------------
// Each wave owns 8 nodes: 16 M-rows (rows 0..7 = batch0, 8..15 = batch1 of nodes n8..n8+7).
// ALL loads (32 B-frags + A-frags + bias + gamma/beta) are issued up-front, then
// sched_barrier(0) pins them there (the scheduler would otherwise sink the B-loads back
// next to each MFMA use, as round-6's VGPR_Count=64 proved). One vmcnt drain, ~40 loads
// in flight, then 32 back-to-back register MFMAs.
template<int IN_BF16>
__global__ __launch_bounds__(256, 1) void k_gemm_bn_gelu(
    const void* __restrict__ Xv, const u16* __restrict__ Wp,
    const float* __restrict__ bias, const float* __restrict__ gamma, const float* __restrict__ beta,
    u16* __restrict__ Out, int N)
{
    __shared__ u16 T[4][16][TPAD];

    const int tid = threadIdx.x;
    const int w = tid >> 6;
    const int l = tid & 63;
    const int g = l >> 4;
    const int c = l & 15;
    const int n8 = blockIdx.x * 32 + w * 8;
    const bool valid = n8 < N;          // uniform across the wave (N % 8 == 0)
    const int nbase = valid ? n8 : 0;

    // ---- ALL B fragments -> registers (32 x bf16x8 = 128 VGPRs), independent loads ----
    bf16x8 B[32];
    #pragma unroll
    for (int i = 0; i < 32; ++i)
        B[i] = *(const bf16x8*)(Wp + ((size_t)i * 64 + l) * 8);

    // ---- A fragment: lane row = c -> (batch = c>>3, node = nbase + (c&7)) ----
    const int ab = c >> 3;
    const int an = nbase + (c & 7);

    bf16x8 af[4];
    if (IN_BF16) {
        const u16* X = (const u16*)Xv;
        const u16* base = X + ((size_t)ab * N + an) * CC + g * 8;
        #pragma unroll
        for (int s = 0; s < 4; ++s) af[s] = *(const bf16x8*)(base + s * 32);
    } else {
        const float* X = (const float*)Xv;
        const float* base = X + ((size_t)ab * N + an) * CC + g * 8;
        float4 lo[4], hi[4];
        #pragma unroll
        for (int s = 0; s < 4; ++s) {
            lo[s] = *(const float4*)(base + s * 32);
            hi[s] = *(const float4*)(base + s * 32 + 4);
        }
        #pragma unroll
        for (int s = 0; s < 4; ++s) {
            bf16x8 v;
            v[0] = (short)f2bf(lo[s].x); v[1] = (short)f2bf(lo[s].y);
            v[2] = (short)f2bf(lo[s].z); v[3] = (short)f2bf(lo[s].w);
            v[4] = (short)f2bf(hi[s].x); v[5] = (short)f2bf(hi[s].y);
            v[6] = (short)f2bf(hi[s].z); v[7] = (short)f2bf(hi[s].w);
            af[s] = v;
        }
    }

    // ---- epilogue params, loaded early so they ride the same latency window ----
    float bb[8];
    #pragma unroll
    for (int t = 0; t < 8; ++t) bb[t] = bias[t * 16 + c];
    float gam[4], bet[4];
    #pragma unroll
    for (int r = 0; r < 4; ++r) {
        int p = (4 * g + r) & 7;
        gam[r] = gamma[nbase + p];
        bet[r] = beta[nbase + p];
    }

    // ---- pin: nothing above may sink below, nothing below may hoist above ----
    __builtin_amdgcn_sched_barrier(0);

    // ---- MFMA: 32 back-to-back, pure register operands ----
    f32x4 acc[8];
    #pragma unroll
    for (int t = 0; t < 8; ++t) acc[t] = (f32x4){0.f, 0.f, 0.f, 0.f};

    #pragma unroll
    for (int s = 0; s < 4; ++s)
        #pragma unroll
        for (int t = 0; t < 8; ++t)
            acc[t] = __builtin_amdgcn_mfma_f32_16x16x32_bf16(af[s], B[t * 4 + s], acc[t], 0, 0, 0);

    // ---- + bias, per-row partial stats ----
    float rs[4] = {0.f, 0.f, 0.f, 0.f}, rq[4] = {0.f, 0.f, 0.f, 0.f};
    #pragma unroll
    for (int t = 0; t < 8; ++t)
        #pragma unroll
        for (int r = 0; r < 4; ++r) {
            float h = acc[t][r] + bb[t];
            acc[t][r] = h;
            rs[r] += h;
            rq[r] += h * h;
        }
    // reduce over the 16 col-lanes, then merge batch halves (row <-> row±8 is lane^32)
    #pragma unroll
    for (int d = 1; d < 16; d <<= 1) {
        #pragma unroll
        for (int r = 0; r < 4; ++r) {
            rs[r] += __shfl_xor(rs[r], d);
            rq[r] += __shfl_xor(rq[r], d);
        }
    }
    #pragma unroll
    for (int r = 0; r < 4; ++r) {
        rs[r] += __shfl_xor(rs[r], 32);
        rq[r] += __shfl_xor(rq[r], 32);
    }

    // ---- per-node BN params, fully in-register ----
    float sc[4], sh[4];
    #pragma unroll
    for (int r = 0; r < 4; ++r) {
        float mean = rs[r] * (1.f / 256.f);
        float var  = rq[r] * (1.f / 256.f) - mean * mean;   // biased, torch-style
        float s_ = gam[r] * rsqrtf(fmaxf(var, 0.f) + 1e-5f);
        sc[r] = s_;
        sh[r] = bet[r] - mean * s_;
    }

    // ---- BN + GELU -> bf16 into this wave's LDS tile ----
    #pragma unroll
    for (int r = 0; r < 4; ++r) {
        int row = 4 * g + r;
        #pragma unroll
        for (int t = 0; t < 8; ++t) {
            float y = acc[t][r] * sc[r] + sh[r];
            T[w][row][t * 16 + c] = f2bf(gelu_f(y));
        }
    }
    __syncthreads();

    // ---- coalesced store: 4 iters x 64 lanes x 16B = 4KB per wave ----
    if (valid) {
        #pragma unroll
        for (int it = 0; it < 4; ++it) {
            int chunk = it * 64 + l;
            int rowi = chunk >> 4;            // 0..15
            int offc = (chunk & 15) * 8;      // u16 offset
            int db = rowi >> 3;
            int dn = n8 + (rowi & 7);
            bf16x4 lo = *(const bf16x4*)&T[w][rowi][offc];
            bf16x4 hi = *(const bf16x4*)&T[w][rowi][offc + 4];
            bf16x8 v;
            v[0] = lo[0]; v[1] = lo[1]; v[2] = lo[2]; v[3] = lo[3];
            v[4] = hi[0]; v[5] = hi[1]; v[6] = hi[2]; v[7] = hi[3];
            *(bf16x8*)(Out + ((size_t)db * N + dn) * CC + offc) = v;
        }
    }
}

// ---------------- per-dst aggregation (no atomics) ----------------
// 1 wave/node, 2 edges in parallel: lane = (parity = l>>5, batch = (l>>4)&1, 8 ch).
// 8 edges per iteration -> 4 x 1KB wave-loads in flight; parity merged by shfl_xor(32).
template<int OUT_F32>
__global__ __launch_bounds__(256) void k_aggregate(
    const u16* __restrict__ A, const int* __restrict__ off,
    const int2* __restrict__ eg, void* __restrict__ Outv, int N)
{
    int n = blockIdx.x * 4 + (threadIdx.x >> 6);
    if (n >= N) return;
    int l = threadIdx.x & 63;
    int p = l >> 5;
    int b = (l >> 4) & 1;
    int ch0 = (l & 15) * 8;
    const u16* Ab = A + (size_t)b * N * CC + ch0;
    int s = off[n], e = off[n + 1];
    float a[8] = {0.f, 0.f, 0.f, 0.f, 0.f, 0.f, 0.f, 0.f};
    for (int j = s; j < e; j += 8) {
        int i0 = j + p, i1 = j + 2 + p, i2 = j + 4 + p, i3 = j + 6 + p;
        int2 e0 = (i0 < e) ? eg[i0] : make_int2(0, 0);
        int2 e1 = (i1 < e) ? eg[i1] : make_int2(0, 0);
        int2 e2 = (i2 < e) ? eg[i2] : make_int2(0, 0);
        int2 e3 = (i3 < e) ? eg[i3] : make_int2(0, 0);
        bf16x8 v0 = *(const bf16x8*)(Ab + (size_t)e0.x * CC);
        bf16x8 v1 = *(const bf16x8*)(Ab + (size_t)e1.x * CC);
        bf16x8 v2 = *(const bf16x8*)(Ab + (size_t)e2.x * CC);
        bf16x8 v3 = *(const bf16x8*)(Ab + (size_t)e3.x * CC);
        float w0 = __int_as_float(e0.y), w1 = __int_as_float(e1.y);
        float w2 = __int_as_float(e2.y), w3 = __int_as_float(e3.y);
        #pragma unroll
        for (int q = 0; q < 8; ++q) {
            a[q] = fmaf(w0, bf2f((u16)v0[q]), a[q]);
            a[q] = fmaf(w1, bf2f((u16)v1[q]), a[q]);
            a[q] = fmaf(w2, bf2f((u16)v2[q]), a[q]);
            a[q] = fmaf(w3, bf2f((u16)v3[q]), a[q]);
        }
    }
    #pragma unroll
    for (int q = 0; q < 8; ++q) a[q] += __shfl_xor(a[q], 32);
    if (l < 32) {
        if (OUT_F32) {
            float* d = (float*)Outv + ((size_t)b * N + n) * CC + ch0;
            *(float4*)&d[0] = make_float4(a[0], a[1], a[2], a[3]);
            *(float4*)&d[4] = make_float4(a[4], a[5], a[6], a[7]);
        } else {
            u16* d = (u16*)Outv + ((size_t)b * N + n) * CC + ch0;
            bf16x8 v;
            #pragma unroll
            for (int q = 0; q < 8; ++q) v[q] = (short)f2bf(a[q]);
            *(bf16x8*)d = v;
        }
    }
}

// ---------------- launch ----------------

extern "C" void kernel_launch(void* const* d_in, const int* in_sizes, int n_in,
                              void* d_out, int out_size, void* d_ws, size_t ws_size,
                              hipStream_t stream)
{
    const float* x   = (const float*)d_in[0];
    const int*   ei  = (const int*)d_in[1];
    const float* nrm = (const float*)d_in[2];
    const float* W1  = (const float*)d_in[3];
    const float* b1  = (const float*)d_in[4];
    const float* g1  = (const float*)d_in[5];
    const float* be1 = (const float*)d_in[6];
    const float* W2  = (const float*)d_in[7];
    const float* b2  = (const float*)d_in[8];
    const float* g2  = (const float*)d_in[9];
    const float* be2 = (const float*)d_in[10];

    const int N = in_sizes[5];   // g1 has N elements
    const int E = in_sizes[2];   // norm has E elements
    const int* row = ei;         // edge_index[0] = scatter dst
    const int* col = ei + E;     // edge_index[1] = gather src
    const int nb = (N + 1023) / 1024;

    auto al = [](size_t v) { return (v + 255) & ~(size_t)255; };
    char* p = (char*)d_ws;
    int* off    = (int*)p;   p += al((size_t)(N + 1) * 4);
    int* cur    = (int*)p;   p += al((size_t)N * 4);
    int2* eg    = (int2*)p;  p += al((size_t)E * 8);
    int* bsum   = (int*)p;   p += al((size_t)nb * 4);
    int* boff   = (int*)p;   p += al((size_t)nb * 4);
    u16* Wp1    = (u16*)p;   p += al((size_t)CC * CC * 2);
    u16* Wp2    = (u16*)p;   p += al((size_t)CC * CC * 2);
    u16* bufA   = (u16*)p;   p += al((size_t)2 * N * CC * 2);
    u16* bufB   = (u16*)p;   p += al((size_t)2 * N * CC * 2);

    // CSR by destination (rebuilt every call; deterministic work)
    k_zero_i32<<<(N + 255) / 256, 256, 0, stream>>>(cur, N);
    k_hist<<<(E + 255) / 256, 256, 0, stream>>>(row, cur, E);
    k_scan_a<<<nb, 256, 0, stream>>>(cur, bsum, N);
    k_scan_b<<<1, 64, 0, stream>>>(bsum, boff, off, N, nb);
    k_scan_c<<<nb, 256, 0, stream>>>(cur, boff, off, N);   // also zeroes cur
    k_fill<<<(E + 255) / 256, 256, 0, stream>>>(row, col, nrm, off, cur, eg, E);

    // W -> bf16 fragment-order repack (both layers, one launch)
    k_wrepack<<<(2 * CC * CC + 255) / 256, 256, 0, stream>>>(W1, Wp1, W2, Wp2);

    const int gb = (N + 31) / 32;
    const int ga = (N + 3) / 4;
    // layer 1
    k_gemm_bn_gelu<0><<<gb, 256, 0, stream>>>(x, Wp1, b1, g1, be1, bufA, N);
    k_aggregate<0><<<ga, 256, 0, stream>>>(bufA, off, eg, bufB, N);
    // layer 2
    k_gemm_bn_gelu<1><<<gb, 256, 0, stream>>>(bufB, Wp2, b2, g2, be2, bufA, N);
    k_aggregate<1><<<ga, 256, 0, stream>>>(bufA, off, eg, (float*)d_out, N);
}

// Round 8
// 169.940 us; speedup vs baseline: 1.0339x; 1.0339x over previous
//
#include <hip/hip_runtime.h>
#include <math.h>

#define CC 128      // channels (FIN=HID=OUT)
#define TPAD 132    // LDS transpose row stride (u16): 264B, 8B-aligned, 2-way-free banks

typedef unsigned short u16;
typedef short bf16x8 __attribute__((ext_vector_type(8)));
typedef short bf16x4 __attribute__((ext_vector_type(4)));
typedef float f32x4 __attribute__((ext_vector_type(4)));

typedef __attribute__((address_space(3))) void lds_t;
typedef const __attribute__((address_space(1))) void gbl_t;

__device__ __forceinline__ u16 f2bf(float f) {
    union { float f; unsigned u; } v; v.f = f;
    unsigned u = v.u;
    return (u16)((u + 0x7FFFu + ((u >> 16) & 1u)) >> 16);   // RNE
}
__device__ __forceinline__ float bf2f(unsigned hi16) {
    union { unsigned u; float f; } v; v.u = hi16 << 16; return v.f;
}

// Exact-GELU via branch-free A&S 7.1.26 erf (|err| < 1.5e-7, far below bf16 noise).
__device__ __forceinline__ float gelu_f(float y) {
    float xa = fabsf(y) * 0.70710678118654752f;
    float t  = __builtin_amdgcn_rcpf(fmaf(0.3275911f, xa, 1.0f));
    float p  = fmaf(1.061405429f, t, -1.453152027f);
    p = fmaf(p, t, 1.421413741f);
    p = fmaf(p, t, -0.284496736f);
    p = fmaf(p, t, 0.254829592f);
    p *= t;
    float e  = __expf(-xa * xa);
    float er = fmaf(-p, e, 1.0f);          // erf(|x|)
    float s  = copysignf(er, y);
    return 0.5f * y * (1.0f + s);
}

// ---------------- CSR build ----------------

__global__ __launch_bounds__(256) void k_zero_i32(int* __restrict__ p, int n) {
    int i = blockIdx.x * 256 + threadIdx.x;
    if (i < n) p[i] = 0;
}

__global__ __launch_bounds__(256) void k_hist(const int* __restrict__ row, int* __restrict__ cnt, int E) {
    int e = blockIdx.x * 256 + threadIdx.x;
    if (e < E) atomicAdd(&cnt[row[e]], 1);
}

__device__ __forceinline__ int wave_incl_scan(int v) {
    #pragma unroll
    for (int d = 1; d < 64; d <<= 1) {
        int t = __shfl_up(v, d);
        if ((threadIdx.x & 63) >= d) v += t;
    }
    return v;
}

__global__ __launch_bounds__(256) void k_scan_a(const int* __restrict__ cnt, int* __restrict__ bsum, int N) {
    int base = blockIdx.x * 1024 + threadIdx.x * 4;
    int s = 0;
    #pragma unroll
    for (int u = 0; u < 4; ++u) { int i = base + u; if (i < N) s += cnt[i]; }
    #pragma unroll
    for (int d = 32; d > 0; d >>= 1) s += __shfl_down(s, d);
    __shared__ int wsum[4];
    if ((threadIdx.x & 63) == 0) wsum[threadIdx.x >> 6] = s;
    __syncthreads();
    if (threadIdx.x == 0) bsum[blockIdx.x] = wsum[0] + wsum[1] + wsum[2] + wsum[3];
}

__global__ __launch_bounds__(64) void k_scan_b(const int* __restrict__ bsum, int* __restrict__ boff,
                                               int* __restrict__ off, int N, int nb) {
    int carry = 0;
    for (int base = 0; base < nb; base += 64) {
        int t = base + (int)threadIdx.x;
        int v = (t < nb) ? bsum[t] : 0;
        int incl = wave_incl_scan(v);
        if (t < nb) boff[t] = carry + incl - v;
        carry += __shfl(incl, 63);
    }
    if (threadIdx.x == 0) off[N] = carry;
}

// local scan + global offset -> off[i]; also zeroes cnt for the subsequent k_fill
__global__ __launch_bounds__(256) void k_scan_c(int* __restrict__ cnt, const int* __restrict__ boff,
                                                int* __restrict__ off, int N) {
    int t = threadIdx.x;
    int base = blockIdx.x * 1024 + t * 4;
    int v[4]; int s = 0;
    #pragma unroll
    for (int u = 0; u < 4; ++u) { int i = base + u; v[u] = (i < N) ? cnt[i] : 0; s += v[u]; }
    int incl = wave_incl_scan(s);
    __shared__ int wsum[4];
    int w = t >> 6, lane = t & 63;
    if (lane == 63) wsum[w] = incl;
    __syncthreads();
    int run = incl - s + boff[blockIdx.x];
    for (int ww = 0; ww < w; ++ww) run += wsum[ww];
    #pragma unroll
    for (int u = 0; u < 4; ++u) {
        int i = base + u;
        if (i < N) { off[i] = run; cnt[i] = 0; }
        run += v[u];
    }
}

// packed edge list: .x = src col, .y = weight bits
__global__ __launch_bounds__(256) void k_fill(const int* __restrict__ row, const int* __restrict__ col,
                                              const float* __restrict__ nrm, const int* __restrict__ off,
                                              int* __restrict__ cur, int2* __restrict__ eg, int E) {
    int e = blockIdx.x * 256 + threadIdx.x;
    if (e < E) {
        int r = row[e];
        int p = off[r] + atomicAdd(&cur[r], 1);
        eg[p] = make_int2(col[e], __float_as_int(nrm[e]));
    }
}

// ---------------- W1,W2 -> bf16, repacked into MFMA B-fragment order ----------------
// Wp[((t*4+s)*64 + l)*8 + j] = bf16( W[16t + (l&15)][s*32 + (l>>4)*8 + j] )
__global__ __launch_bounds__(256) void k_wrepack(const float* __restrict__ W1, u16* __restrict__ Wp1,
                                                 const float* __restrict__ W2, u16* __restrict__ Wp2) {
    int i = blockIdx.x * 256 + threadIdx.x;
    const float* W = (i < CC * CC) ? W1 : W2;
    u16* Wp = (i < CC * CC) ? Wp1 : Wp2;
    int ii = (i < CC * CC) ? i : i - CC * CC;
    if (ii < CC * CC) {
        int j = ii & 7, l = (ii >> 3) & 63, s = (ii >> 9) & 3, t = ii >> 11;
        int r = 16 * t + (l & 15);
        int k = s * 32 + (l >> 4) * 8 + j;
        Wp[ii] = f2bf(W[r * CC + k]);
    }
}

// ---------------- fused MFMA GEMM + BatchNorm + GELU (LDS-resident W) ----------------
// Each wave owns 8 nodes: 16 M-rows (rows 0..7 = batch0, 8..15 = batch1 of nodes n8..n8+7).
// The whole 128x128 bf16 W (32KB, fragment-order) is staged into LDS once per block via
// global_load_lds(width=16); B-frags are conflict-free ds_read_b128 (~12cy throughput)
// that the compiler schedules with fine-grained lgkmcnt. VGPRs stay ~100 -> 4 waves/SIMD,
// so ds_read latency is hidden by TLP instead of fought with register heroics (r5-r7 lesson).
// After the MFMA loop the same 32KB LDS is reused as the store-transpose buffer.
template<int IN_BF16>
__global__ __launch_bounds__(256, 4) void k_gemm_bn_gelu(
    const void* __restrict__ Xv, const u16* __restrict__ Wp,
    const float* __restrict__ bias, const float* __restrict__ gamma, const float* __restrict__ beta,
    u16* __restrict__ Out, int N)
{
    __shared__ __align__(16) u16 SM[CC * CC];   // 32KB: W during MFMA, transpose buf in epilogue

    const int tid = threadIdx.x;
    const int w = tid >> 6;
    const int l = tid & 63;
    const int g = l >> 4;
    const int c = l & 15;
    const int n8 = blockIdx.x * 32 + w * 8;
    const bool valid = n8 < N;          // uniform across the wave
    const int nbase = valid ? n8 : 0;

    // ---- stage W -> LDS: 8 iters x (4 waves x 64 lanes x 16B) = 32KB, async DMA ----
    #pragma unroll
    for (int it = 0; it < 8; ++it) {
        const u16* gsrc = Wp + it * 2048 + w * 512 + l * 8;   // per-lane global addr
        u16* ldst = &SM[it * 2048 + w * 512];                 // wave-uniform LDS base
        __builtin_amdgcn_global_load_lds((gbl_t*)gsrc, (lds_t*)ldst, 16, 0, 0);
    }

    // ---- A fragment (rides under the staging DMA): lane row = c ----
    const int ab = c >> 3;
    const int an = nbase + (c & 7);

    bf16x8 af[4];
    if (IN_BF16) {
        const u16* X = (const u16*)Xv;
        const u16* base = X + ((size_t)ab * N + an) * CC + g * 8;
        #pragma unroll
        for (int s = 0; s < 4; ++s) af[s] = *(const bf16x8*)(base + s * 32);
    } else {
        const float* X = (const float*)Xv;
        const float* base = X + ((size_t)ab * N + an) * CC + g * 8;
        float4 lo[4], hi[4];
        #pragma unroll
        for (int s = 0; s < 4; ++s) {
            lo[s] = *(const float4*)(base + s * 32);
            hi[s] = *(const float4*)(base + s * 32 + 4);
        }
        #pragma unroll
        for (int s = 0; s < 4; ++s) {
            bf16x8 v;
            v[0] = (short)f2bf(lo[s].x); v[1] = (short)f2bf(lo[s].y);
            v[2] = (short)f2bf(lo[s].z); v[3] = (short)f2bf(lo[s].w);
            v[4] = (short)f2bf(hi[s].x); v[5] = (short)f2bf(hi[s].y);
            v[6] = (short)f2bf(hi[s].z); v[7] = (short)f2bf(hi[s].w);
            af[s] = v;
        }
    }

    // epilogue params (small, cached)
    float bb[8];
    #pragma unroll
    for (int t = 0; t < 8; ++t) bb[t] = bias[t * 16 + c];
    float gam[4], bet[4];
    #pragma unroll
    for (int r = 0; r < 4; ++r) {
        int p = (4 * g + r) & 7;
        gam[r] = gamma[nbase + p];
        bet[r] = beta[nbase + p];
    }

    __syncthreads();   // staging DMA drained (vmcnt0) + all waves see W in LDS

    // ---- MFMA: B-frags via conflict-free ds_read_b128 ----
    f32x4 acc[8];
    #pragma unroll
    for (int t = 0; t < 8; ++t) acc[t] = (f32x4){0.f, 0.f, 0.f, 0.f};

    #pragma unroll
    for (int s = 0; s < 4; ++s) {
        bf16x8 bf[8];
        #pragma unroll
        for (int t = 0; t < 8; ++t)
            bf[t] = *(const bf16x8*)&SM[((t * 4 + s) * 64 + l) * 8];
        #pragma unroll
        for (int t = 0; t < 8; ++t)
            acc[t] = __builtin_amdgcn_mfma_f32_16x16x32_bf16(af[s], bf[t], acc[t], 0, 0, 0);
    }

    // ---- + bias, per-row partial stats ----
    float rs[4] = {0.f, 0.f, 0.f, 0.f}, rq[4] = {0.f, 0.f, 0.f, 0.f};
    #pragma unroll
    for (int t = 0; t < 8; ++t)
        #pragma unroll
        for (int r = 0; r < 4; ++r) {
            float h = acc[t][r] + bb[t];
            acc[t][r] = h;
            rs[r] += h;
            rq[r] += h * h;
        }
    // reduce over the 16 col-lanes, then merge batch halves (row <-> row±8 is lane^32)
    #pragma unroll
    for (int d = 1; d < 16; d <<= 1) {
        #pragma unroll
        for (int r = 0; r < 4; ++r) {
            rs[r] += __shfl_xor(rs[r], d);
            rq[r] += __shfl_xor(rq[r], d);
        }
    }
    #pragma unroll
    for (int r = 0; r < 4; ++r) {
        rs[r] += __shfl_xor(rs[r], 32);
        rq[r] += __shfl_xor(rq[r], 32);
    }

    // ---- per-node BN params, fully in-register ----
    float sc[4], sh[4];
    #pragma unroll
    for (int r = 0; r < 4; ++r) {
        float mean = rs[r] * (1.f / 256.f);
        float var  = rq[r] * (1.f / 256.f) - mean * mean;   // biased, torch-style
        float s_ = gam[r] * rsqrtf(fmaxf(var, 0.f) + 1e-5f);
        sc[r] = s_;
        sh[r] = bet[r] - mean * s_;
    }

    __syncthreads();   // all waves done reading W from LDS; safe to overwrite with T

    // ---- BN + GELU -> bf16 into this wave's region of the (reused) LDS ----
    u16 (*T)[TPAD] = (u16 (*)[TPAD])(SM + w * 16 * TPAD);
    #pragma unroll
    for (int r = 0; r < 4; ++r) {
        int row = 4 * g + r;
        #pragma unroll
        for (int t = 0; t < 8; ++t) {
            float y = acc[t][r] * sc[r] + sh[r];
            T[row][t * 16 + c] = f2bf(gelu_f(y));
        }
    }
    // wave-private write->read: compiler orders via lgkmcnt, no barrier needed

    // ---- coalesced store: 4 iters x 64 lanes x 16B = 4KB per wave ----
    if (valid) {
        #pragma unroll
        for (int it = 0; it < 4; ++it) {
            int chunk = it * 64 + l;
            int rowi = chunk >> 4;            // 0..15
            int offc = (chunk & 15) * 8;      // u16 offset
            int db = rowi >> 3;
            int dn = n8 + (rowi & 7);
            bf16x4 lo = *(const bf16x4*)&T[rowi][offc];
            bf16x4 hi = *(const bf16x4*)&T[rowi][offc + 4];
            bf16x8 v;
            v[0] = lo[0]; v[1] = lo[1]; v[2] = lo[2]; v[3] = lo[3];
            v[4] = hi[0]; v[5] = hi[1]; v[6] = hi[2]; v[7] = hi[3];
            *(bf16x8*)(Out + ((size_t)db * N + dn) * CC + offc) = v;
        }
    }
}

// ---------------- per-dst aggregation (no atomics) ----------------
// 1 wave/node, 2 edges in parallel: lane = (parity = l>>5, batch = (l>>4)&1, 8 ch).
// 8 edges per iteration -> 4 x 1KB wave-loads in flight; parity merged by shfl_xor(32).
template<int OUT_F32>
__global__ __launch_bounds__(256) void k_aggregate(
    const u16* __restrict__ A, const int* __restrict__ off,
    const int2* __restrict__ eg, void* __restrict__ Outv, int N)
{
    int n = blockIdx.x * 4 + (threadIdx.x >> 6);
    if (n >= N) return;
    int l = threadIdx.x & 63;
    int p = l >> 5;
    int b = (l >> 4) & 1;
    int ch0 = (l & 15) * 8;
    const u16* Ab = A + (size_t)b * N * CC + ch0;
    int s = off[n], e = off[n + 1];
    float a[8] = {0.f, 0.f, 0.f, 0.f, 0.f, 0.f, 0.f, 0.f};
    for (int j = s; j < e; j += 8) {
        int i0 = j + p, i1 = j + 2 + p, i2 = j + 4 + p, i3 = j + 6 + p;
        int2 e0 = (i0 < e) ? eg[i0] : make_int2(0, 0);
        int2 e1 = (i1 < e) ? eg[i1] : make_int2(0, 0);
        int2 e2 = (i2 < e) ? eg[i2] : make_int2(0, 0);
        int2 e3 = (i3 < e) ? eg[i3] : make_int2(0, 0);
        bf16x8 v0 = *(const bf16x8*)(Ab + (size_t)e0.x * CC);
        bf16x8 v1 = *(const bf16x8*)(Ab + (size_t)e1.x * CC);
        bf16x8 v2 = *(const bf16x8*)(Ab + (size_t)e2.x * CC);
        bf16x8 v3 = *(const bf16x8*)(Ab + (size_t)e3.x * CC);
        float w0 = __int_as_float(e0.y), w1 = __int_as_float(e1.y);
        float w2 = __int_as_float(e2.y), w3 = __int_as_float(e3.y);
        #pragma unroll
        for (int q = 0; q < 8; ++q) {
            a[q] = fmaf(w0, bf2f((u16)v0[q]), a[q]);
            a[q] = fmaf(w1, bf2f((u16)v1[q]), a[q]);
            a[q] = fmaf(w2, bf2f((u16)v2[q]), a[q]);
            a[q] = fmaf(w3, bf2f((u16)v3[q]), a[q]);
        }
    }
    #pragma unroll
    for (int q = 0; q < 8; ++q) a[q] += __shfl_xor(a[q], 32);
    if (l < 32) {
        if (OUT_F32) {
            float* d = (float*)Outv + ((size_t)b * N + n) * CC + ch0;
            *(float4*)&d[0] = make_float4(a[0], a[1], a[2], a[3]);
            *(float4*)&d[4] = make_float4(a[4], a[5], a[6], a[7]);
        } else {
            u16* d = (u16*)Outv + ((size_t)b * N + n) * CC + ch0;
            bf16x8 v;
            #pragma unroll
            for (int q = 0; q < 8; ++q) v[q] = (short)f2bf(a[q]);
            *(bf16x8*)d = v;
        }
    }
}

// ---------------- launch ----------------

extern "C" void kernel_launch(void* const* d_in, const int* in_sizes, int n_in,
                              void* d_out, int out_size, void* d_ws, size_t ws_size,
                              hipStream_t stream)
{
    const float* x   = (const float*)d_in[0];
    const int*   ei  = (const int*)d_in[1];
    const float* nrm = (const float*)d_in[2];
    const float* W1  = (const float*)d_in[3];
    const float* b1  = (const float*)d_in[4];
    const float* g1  = (const float*)d_in[5];
    const float* be1 = (const float*)d_in[6];
    const float* W2  = (const float*)d_in[7];
    const float* b2  = (const float*)d_in[8];
    const float* g2  = (const float*)d_in[9];
    const float* be2 = (const float*)d_in[10];

    const int N = in_sizes[5];   // g1 has N elements
    const int E = in_sizes[2];   // norm has E elements
    const int* row = ei;         // edge_index[0] = scatter dst
    const int* col = ei + E;     // edge_index[1] = gather src
    const int nb = (N + 1023) / 1024;

    auto al = [](size_t v) { return (v + 255) & ~(size_t)255; };
    char* p = (char*)d_ws;
    int* off    = (int*)p;   p += al((size_t)(N + 1) * 4);
    int* cur    = (int*)p;   p += al((size_t)N * 4);
    int2* eg    = (int2*)p;  p += al((size_t)E * 8);
    int* bsum   = (int*)p;   p += al((size_t)nb * 4);
    int* boff   = (int*)p;   p += al((size_t)nb * 4);
    u16* Wp1    = (u16*)p;   p += al((size_t)CC * CC * 2);
    u16* Wp2    = (u16*)p;   p += al((size_t)CC * CC * 2);
    u16* bufA   = (u16*)p;   p += al((size_t)2 * N * CC * 2);
    u16* bufB   = (u16*)p;   p += al((size_t)2 * N * CC * 2);

    // CSR by destination (rebuilt every call; deterministic work)
    k_zero_i32<<<(N + 255) / 256, 256, 0, stream>>>(cur, N);
    k_hist<<<(E + 255) / 256, 256, 0, stream>>>(row, cur, E);
    k_scan_a<<<nb, 256, 0, stream>>>(cur, bsum, N);
    k_scan_b<<<1, 64, 0, stream>>>(bsum, boff, off, N, nb);
    k_scan_c<<<nb, 256, 0, stream>>>(cur, boff, off, N);   // also zeroes cur
    k_fill<<<(E + 255) / 256, 256, 0, stream>>>(row, col, nrm, off, cur, eg, E);

    // W -> bf16 fragment-order repack (both layers, one launch)
    k_wrepack<<<(2 * CC * CC + 255) / 256, 256, 0, stream>>>(W1, Wp1, W2, Wp2);

    const int gb = (N + 31) / 32;
    const int ga = (N + 3) / 4;
    // layer 1
    k_gemm_bn_gelu<0><<<gb, 256, 0, stream>>>(x, Wp1, b1, g1, be1, bufA, N);
    k_aggregate<0><<<ga, 256, 0, stream>>>(bufA, off, eg, bufB, N);
    // layer 2
    k_gemm_bn_gelu<1><<<gb, 256, 0, stream>>>(bufB, Wp2, b2, g2, be2, bufA, N);
    k_aggregate<1><<<ga, 256, 0, stream>>>(bufA, off, eg, (float*)d_out, N);
}

// Round 9
// 160.560 us; speedup vs baseline: 1.0943x; 1.0584x over previous
//
#include <hip/hip_runtime.h>
#include <math.h>

#define CC 128      // channels (FIN=HID=OUT)

typedef unsigned short u16;
typedef short bf16x8 __attribute__((ext_vector_type(8)));
typedef float f32x4 __attribute__((ext_vector_type(4)));

typedef __attribute__((address_space(3))) void lds_t;
typedef const __attribute__((address_space(1))) void gbl_t;

__device__ __forceinline__ u16 f2bf(float f) {
    union { float f; unsigned u; } v; v.f = f;
    unsigned u = v.u;
    return (u16)((u + 0x7FFFu + ((u >> 16) & 1u)) >> 16);   // RNE
}
__device__ __forceinline__ float bf2f(unsigned hi16) {
    union { unsigned u; float f; } v; v.u = hi16 << 16; return v.f;
}
// HW packed f32->bf16 (RNE): 2 values in 1 instruction.
__device__ __forceinline__ unsigned cvt_pk(float lo, float hi) {
    unsigned r;
    asm("v_cvt_pk_bf16_f32 %0, %1, %2" : "=v"(r) : "v"(lo), "v"(hi));
    return r;
}

// Exact-GELU via branch-free A&S 7.1.26 erf (|err| < 1.5e-7).
__device__ __forceinline__ float gelu_f(float y) {
    float xa = fabsf(y) * 0.70710678118654752f;
    float t  = __builtin_amdgcn_rcpf(fmaf(0.3275911f, xa, 1.0f));
    float p  = fmaf(1.061405429f, t, -1.453152027f);
    p = fmaf(p, t, 1.421413741f);
    p = fmaf(p, t, -0.284496736f);
    p = fmaf(p, t, 0.254829592f);
    p *= t;
    float e  = __expf(-xa * xa);
    float er = fmaf(-p, e, 1.0f);
    float s  = copysignf(er, y);
    return 0.5f * y * (1.0f + s);
}

// ---------------- CSR build ----------------

__global__ __launch_bounds__(256) void k_zero_i32(int* __restrict__ p, int n) {
    int i = blockIdx.x * 256 + threadIdx.x;
    if (i < n) p[i] = 0;
}

__global__ __launch_bounds__(256) void k_hist(const int* __restrict__ row, int* __restrict__ cnt, int E) {
    int e = blockIdx.x * 256 + threadIdx.x;
    if (e < E) atomicAdd(&cnt[row[e]], 1);
}

__device__ __forceinline__ int wave_incl_scan(int v) {
    #pragma unroll
    for (int d = 1; d < 64; d <<= 1) {
        int t = __shfl_up(v, d);
        if ((threadIdx.x & 63) >= d) v += t;
    }
    return v;
}

__global__ __launch_bounds__(256) void k_scan_a(const int* __restrict__ cnt, int* __restrict__ bsum, int N) {
    int base = blockIdx.x * 1024 + threadIdx.x * 4;
    int s = 0;
    #pragma unroll
    for (int u = 0; u < 4; ++u) { int i = base + u; if (i < N) s += cnt[i]; }
    #pragma unroll
    for (int d = 32; d > 0; d >>= 1) s += __shfl_down(s, d);
    __shared__ int wsum[4];
    if ((threadIdx.x & 63) == 0) wsum[threadIdx.x >> 6] = s;
    __syncthreads();
    if (threadIdx.x == 0) bsum[blockIdx.x] = wsum[0] + wsum[1] + wsum[2] + wsum[3];
}

__global__ __launch_bounds__(64) void k_scan_b(const int* __restrict__ bsum, int* __restrict__ boff,
                                               int* __restrict__ off, int N, int nb) {
    int carry = 0;
    for (int base = 0; base < nb; base += 64) {
        int t = base + (int)threadIdx.x;
        int v = (t < nb) ? bsum[t] : 0;
        int incl = wave_incl_scan(v);
        if (t < nb) boff[t] = carry + incl - v;
        carry += __shfl(incl, 63);
    }
    if (threadIdx.x == 0) off[N] = carry;
}

__global__ __launch_bounds__(256) void k_scan_c(int* __restrict__ cnt, const int* __restrict__ boff,
                                                int* __restrict__ off, int N) {
    int t = threadIdx.x;
    int base = blockIdx.x * 1024 + t * 4;
    int v[4]; int s = 0;
    #pragma unroll
    for (int u = 0; u < 4; ++u) { int i = base + u; v[u] = (i < N) ? cnt[i] : 0; s += v[u]; }
    int incl = wave_incl_scan(s);
    __shared__ int wsum[4];
    int w = t >> 6, lane = t & 63;
    if (lane == 63) wsum[w] = incl;
    __syncthreads();
    int run = incl - s + boff[blockIdx.x];
    for (int ww = 0; ww < w; ++ww) run += wsum[ww];
    #pragma unroll
    for (int u = 0; u < 4; ++u) {
        int i = base + u;
        if (i < N) { off[i] = run; cnt[i] = 0; }
        run += v[u];
    }
}

__global__ __launch_bounds__(256) void k_fill(const int* __restrict__ row, const int* __restrict__ col,
                                              const float* __restrict__ nrm, const int* __restrict__ off,
                                              int* __restrict__ cur, int2* __restrict__ eg, int E) {
    int e = blockIdx.x * 256 + threadIdx.x;
    if (e < E) {
        int r = row[e];
        int p = off[r] + atomicAdd(&cur[r], 1);
        eg[p] = make_int2(col[e], __float_as_int(nrm[e]));
    }
}

// ---------------- W repack into MFMA B-fragment order ----------------
// W1: standard k-order. W2: k-order permuted by pi(p) = (p&7)*16 + (p>>3), matching the
// channel-permuted layout the fused kernel stores A1/Z in (position p holds channel pi(p)).
__global__ __launch_bounds__(256) void k_wrepack(const float* __restrict__ W1, u16* __restrict__ Wp1,
                                                 const float* __restrict__ W2, u16* __restrict__ Wp2) {
    int i = blockIdx.x * 256 + threadIdx.x;
    if (i < 2 * CC * CC) {
        int is2 = (i >= CC * CC);
        int ii = is2 ? i - CC * CC : i;
        int j = ii & 7, l = (ii >> 3) & 63, s = (ii >> 9) & 3, t = ii >> 11;
        int r = 16 * t + (l & 15);
        int p = s * 32 + ((l >> 4) & 3) * 8 + j;             // fragment k-position 0..127
        if (is2) {
            int k = (p & 7) * 16 + (p >> 3);                 // pi(p)
            Wp2[ii] = f2bf(W2[r * CC + k]);
        } else {
            Wp1[ii] = f2bf(W1[r * CC + p]);
        }
    }
}

// ---------------- K1: GEMM1 + BN1 + GELU1 + GEMM2 (fused, A1 never leaves the kernel) ----
// Each wave owns 8 nodes (16 M-rows: 0..7 batch0, 8..15 batch1). W1 staged to LDS, MFMA
// pass 1, BN+GELU in registers; W2 staged into the SAME LDS region under the epilogue's
// latency; A1 goes through a wave-private LDS tile (conflict-free) into A-fragments for
// MFMA pass 2; Z = A1*W2^T stored in channel-permuted layout -> plain dwordx4 stores.
__global__ __launch_bounds__(256) void k_fused_l1(
    const float* __restrict__ X, const u16* __restrict__ Wp1, const u16* __restrict__ Wp2,
    const float* __restrict__ bias, const float* __restrict__ gamma, const float* __restrict__ beta,
    u16* __restrict__ Z, int N)
{
    __shared__ __align__(16) u16 WS[CC * CC];          // 32KB: W1 in pass1, W2 in pass2
    __shared__ __align__(16) unsigned TT[4][16][68];   // per-wave A1 transpose, 68 u32 stride

    const int tid = threadIdx.x;
    const int w = tid >> 6;
    const int l = tid & 63;
    const int g = l >> 4;
    const int c = l & 15;
    const int n8 = blockIdx.x * 32 + w * 8;
    const bool valid = n8 < N;
    const int nbase = valid ? n8 : 0;

    // ---- stage W1 -> LDS (async DMA, 32KB/block) ----
    #pragma unroll
    for (int it = 0; it < 8; ++it) {
        const u16* gsrc = Wp1 + it * 2048 + w * 512 + l * 8;
        u16* ldst = &WS[it * 2048 + w * 512];
        __builtin_amdgcn_global_load_lds((gbl_t*)gsrc, (lds_t*)ldst, 16, 0, 0);
    }

    // ---- A fragments from X (f32), rides under the DMA ----
    const int ab = c >> 3;
    const int an = nbase + (c & 7);
    const float* xbase = X + ((size_t)ab * N + an) * CC + g * 8;
    bf16x8 af[4];
    #pragma unroll
    for (int s = 0; s < 4; ++s) {
        float4 lo = *(const float4*)(xbase + s * 32);
        float4 hi = *(const float4*)(xbase + s * 32 + 4);
        unsigned aw[4];
        aw[0] = cvt_pk(lo.x, lo.y); aw[1] = cvt_pk(lo.z, lo.w);
        aw[2] = cvt_pk(hi.x, hi.y); aw[3] = cvt_pk(hi.z, hi.w);
        af[s] = *(bf16x8*)aw;
    }

    // epilogue params
    float bb[8];
    #pragma unroll
    for (int t = 0; t < 8; ++t) bb[t] = bias[t * 16 + c];
    float gam[4], bet[4];
    #pragma unroll
    for (int r = 0; r < 4; ++r) {
        int p = (4 * g + r) & 7;
        gam[r] = gamma[nbase + p];
        bet[r] = beta[nbase + p];
    }

    __syncthreads();   // W1 staged (barrier drains vmcnt)

    // ---- MFMA pass 1: h1 = X * W1^T ----
    f32x4 acc[8];
    #pragma unroll
    for (int t = 0; t < 8; ++t) acc[t] = (f32x4){0.f, 0.f, 0.f, 0.f};
    #pragma unroll
    for (int s = 0; s < 4; ++s) {
        bf16x8 bf[8];
        #pragma unroll
        for (int t = 0; t < 8; ++t)
            bf[t] = *(const bf16x8*)&WS[((t * 4 + s) * 64 + l) * 8];
        #pragma unroll
        for (int t = 0; t < 8; ++t)
            acc[t] = __builtin_amdgcn_mfma_f32_16x16x32_bf16(af[s], bf[t], acc[t], 0, 0, 0);
    }

    __syncthreads();   // all waves done reading W1

    // ---- stage W2 into the same LDS region; latency hidden by the epilogue below ----
    #pragma unroll
    for (int it = 0; it < 8; ++it) {
        const u16* gsrc = Wp2 + it * 2048 + w * 512 + l * 8;
        u16* ldst = &WS[it * 2048 + w * 512];
        __builtin_amdgcn_global_load_lds((gbl_t*)gsrc, (lds_t*)ldst, 16, 0, 0);
    }

    // ---- bias + BN1 stats (wave-local shuffle reduce) ----
    float rs[4] = {0.f, 0.f, 0.f, 0.f}, rq[4] = {0.f, 0.f, 0.f, 0.f};
    #pragma unroll
    for (int t = 0; t < 8; ++t)
        #pragma unroll
        for (int r = 0; r < 4; ++r) {
            float h = acc[t][r] + bb[t];
            acc[t][r] = h;
            rs[r] += h;
            rq[r] += h * h;
        }
    #pragma unroll
    for (int d = 1; d < 16; d <<= 1) {
        #pragma unroll
        for (int r = 0; r < 4; ++r) {
            rs[r] += __shfl_xor(rs[r], d);
            rq[r] += __shfl_xor(rq[r], d);
        }
    }
    #pragma unroll
    for (int r = 0; r < 4; ++r) {
        rs[r] += __shfl_xor(rs[r], 32);
        rq[r] += __shfl_xor(rq[r], 32);
    }

    // ---- BN1 + GELU1 in registers ----
    #pragma unroll
    for (int r = 0; r < 4; ++r) {
        float mean = rs[r] * (1.f / 256.f);
        float var  = rq[r] * (1.f / 256.f) - mean * mean;
        float sc = gam[r] * rsqrtf(fmaxf(var, 0.f) + 1e-5f);
        float sh = bet[r] - mean * sc;
        #pragma unroll
        for (int t = 0; t < 8; ++t)
            acc[t][r] = gelu_f(acc[t][r] * sc + sh);
    }

    // ---- A1 -> wave-private LDS tile (permuted: pos c*8+t), then A2-fragments ----
    #pragma unroll
    for (int r = 0; r < 4; ++r) {
        unsigned tw[4];
        #pragma unroll
        for (int tt = 0; tt < 4; ++tt)
            tw[tt] = cvt_pk(acc[2 * tt][r], acc[2 * tt + 1][r]);
        *(uint4*)&TT[w][4 * g + r][c * 4] = *(uint4*)tw;   // ds_write_b128, conflict-free
    }
    bf16x8 af2[4];
    #pragma unroll
    for (int s = 0; s < 4; ++s)
        af2[s] = *(const bf16x8*)&TT[w][c][s * 16 + g * 4];  // same-wave, lgkmcnt-ordered

    __syncthreads();   // W2 staged (vmcnt drained) for everyone

    // ---- MFMA pass 2: Z = A1 * W2^T (k-order = pi, matches Wp2 repack) ----
    f32x4 acc2[8];
    #pragma unroll
    for (int t = 0; t < 8; ++t) acc2[t] = (f32x4){0.f, 0.f, 0.f, 0.f};
    #pragma unroll
    for (int s = 0; s < 4; ++s) {
        bf16x8 bf[8];
        #pragma unroll
        for (int t = 0; t < 8; ++t)
            bf[t] = *(const bf16x8*)&WS[((t * 4 + s) * 64 + l) * 8];
        #pragma unroll
        for (int t = 0; t < 8; ++t)
            acc2[t] = __builtin_amdgcn_mfma_f32_16x16x32_bf16(af2[s], bf[t], acc2[t], 0, 0, 0);
    }

    // ---- store Z in permuted layout: one dwordx4 per row per thread ----
    if (valid) {
        #pragma unroll
        for (int r = 0; r < 4; ++r) {
            int rr = 4 * g + r;
            int db = rr >> 3, dn = n8 + (rr & 7);
            unsigned zw[4];
            #pragma unroll
            for (int tt = 0; tt < 4; ++tt)
                zw[tt] = cvt_pk(acc2[2 * tt][r], acc2[2 * tt + 1][r]);
            *(uint4*)(Z + ((size_t)db * N + dn) * CC + c * 8) = *(uint4*)zw;
        }
    }
}

// ---------------- K2: aggregate(Z) + b2 + BN2 + GELU2 -> a2 (permuted bf16) ----------------
// 1 wave/node; lane = (parity l>>5, batch (l>>4)&1, ch-group l&15). Lane's 8 values are
// channels {t*16+c} (permuted positions c*8+t). BN2 stats via in-wave shuffles (free).
__global__ __launch_bounds__(256) void k_agg_bn(
    const u16* __restrict__ Zin, const int* __restrict__ off, const int2* __restrict__ eg,
    const float* __restrict__ b2, const float* __restrict__ g2, const float* __restrict__ be2,
    u16* __restrict__ A2, int N)
{
    int n = blockIdx.x * 4 + (threadIdx.x >> 6);
    if (n >= N) return;
    int l = threadIdx.x & 63;
    int p = l >> 5;
    int b = (l >> 4) & 1;
    int c = l & 15;
    const u16* Ab = Zin + (size_t)b * N * CC + c * 8;
    int s = off[n], e = off[n + 1];
    float a[8] = {0.f, 0.f, 0.f, 0.f, 0.f, 0.f, 0.f, 0.f};
    for (int j = s; j < e; j += 8) {
        int i0 = j + p, i1 = j + 2 + p, i2 = j + 4 + p, i3 = j + 6 + p;
        int2 e0 = (i0 < e) ? eg[i0] : make_int2(0, 0);
        int2 e1 = (i1 < e) ? eg[i1] : make_int2(0, 0);
        int2 e2 = (i2 < e) ? eg[i2] : make_int2(0, 0);
        int2 e3 = (i3 < e) ? eg[i3] : make_int2(0, 0);
        bf16x8 v0 = *(const bf16x8*)(Ab + (size_t)e0.x * CC);
        bf16x8 v1 = *(const bf16x8*)(Ab + (size_t)e1.x * CC);
        bf16x8 v2 = *(const bf16x8*)(Ab + (size_t)e2.x * CC);
        bf16x8 v3 = *(const bf16x8*)(Ab + (size_t)e3.x * CC);
        float w0 = __int_as_float(e0.y), w1 = __int_as_float(e1.y);
        float w2 = __int_as_float(e2.y), w3 = __int_as_float(e3.y);
        #pragma unroll
        for (int q = 0; q < 8; ++q) {
            a[q] = fmaf(w0, bf2f((u16)v0[q]), a[q]);
            a[q] = fmaf(w1, bf2f((u16)v1[q]), a[q]);
            a[q] = fmaf(w2, bf2f((u16)v2[q]), a[q]);
            a[q] = fmaf(w3, bf2f((u16)v3[q]), a[q]);
        }
    }
    #pragma unroll
    for (int q = 0; q < 8; ++q) a[q] += __shfl_xor(a[q], 32);   // merge parities

    // + b2, BN2 stats over (2 batches x 128 ch) = lanes 0..31 x 8 (dup in 32..63)
    float ss = 0.f, qq = 0.f;
    #pragma unroll
    for (int t = 0; t < 8; ++t) {
        float h = a[t] + b2[t * 16 + c];
        a[t] = h;
        ss += h;
        qq += h * h;
    }
    #pragma unroll
    for (int d = 1; d < 32; d <<= 1) {
        ss += __shfl_xor(ss, d);
        qq += __shfl_xor(qq, d);
    }
    float mean = ss * (1.f / 256.f);
    float var  = qq * (1.f / 256.f) - mean * mean;
    float sc = g2[n] * rsqrtf(fmaxf(var, 0.f) + 1e-5f);
    float sh = be2[n] - mean * sc;

    if (l < 32) {
        unsigned ow[4];
        #pragma unroll
        for (int tt = 0; tt < 4; ++tt) {
            float y0 = gelu_f(a[2 * tt] * sc + sh);
            float y1 = gelu_f(a[2 * tt + 1] * sc + sh);
            ow[tt] = cvt_pk(y0, y1);
        }
        *(uint4*)(A2 + ((size_t)b * N + n) * CC + c * 8) = *(uint4*)ow;
    }
}

// ---------------- K3: aggregate(a2) -> standard-layout f32 output ----------------
__global__ __launch_bounds__(256) void k_agg_out(
    const u16* __restrict__ A2, const int* __restrict__ off, const int2* __restrict__ eg,
    float* __restrict__ Out, int N)
{
    int n = blockIdx.x * 4 + (threadIdx.x >> 6);
    if (n >= N) return;
    int l = threadIdx.x & 63;
    int p = l >> 5;
    int b = (l >> 4) & 1;
    int c = l & 15;
    const u16* Ab = A2 + (size_t)b * N * CC + c * 8;
    int s = off[n], e = off[n + 1];
    float a[8] = {0.f, 0.f, 0.f, 0.f, 0.f, 0.f, 0.f, 0.f};
    for (int j = s; j < e; j += 8) {
        int i0 = j + p, i1 = j + 2 + p, i2 = j + 4 + p, i3 = j + 6 + p;
        int2 e0 = (i0 < e) ? eg[i0] : make_int2(0, 0);
        int2 e1 = (i1 < e) ? eg[i1] : make_int2(0, 0);
        int2 e2 = (i2 < e) ? eg[i2] : make_int2(0, 0);
        int2 e3 = (i3 < e) ? eg[i3] : make_int2(0, 0);
        bf16x8 v0 = *(const bf16x8*)(Ab + (size_t)e0.x * CC);
        bf16x8 v1 = *(const bf16x8*)(Ab + (size_t)e1.x * CC);
        bf16x8 v2 = *(const bf16x8*)(Ab + (size_t)e2.x * CC);
        bf16x8 v3 = *(const bf16x8*)(Ab + (size_t)e3.x * CC);
        float w0 = __int_as_float(e0.y), w1 = __int_as_float(e1.y);
        float w2 = __int_as_float(e2.y), w3 = __int_as_float(e3.y);
        #pragma unroll
        for (int q = 0; q < 8; ++q) {
            a[q] = fmaf(w0, bf2f((u16)v0[q]), a[q]);
            a[q] = fmaf(w1, bf2f((u16)v1[q]), a[q]);
            a[q] = fmaf(w2, bf2f((u16)v2[q]), a[q]);
            a[q] = fmaf(w3, bf2f((u16)v3[q]), a[q]);
        }
    }
    #pragma unroll
    for (int q = 0; q < 8; ++q) a[q] += __shfl_xor(a[q], 32);
    if (l < 32) {
        float* d = Out + ((size_t)b * N + n) * CC + c;   // un-permute: value t -> channel t*16+c
        #pragma unroll
        for (int t = 0; t < 8; ++t) d[t * 16] = a[t];
    }
}

// ---------------- launch ----------------

extern "C" void kernel_launch(void* const* d_in, const int* in_sizes, int n_in,
                              void* d_out, int out_size, void* d_ws, size_t ws_size,
                              hipStream_t stream)
{
    const float* x   = (const float*)d_in[0];
    const int*   ei  = (const int*)d_in[1];
    const float* nrm = (const float*)d_in[2];
    const float* W1  = (const float*)d_in[3];
    const float* b1  = (const float*)d_in[4];
    const float* g1  = (const float*)d_in[5];
    const float* be1 = (const float*)d_in[6];
    const float* W2  = (const float*)d_in[7];
    const float* b2  = (const float*)d_in[8];
    const float* g2  = (const float*)d_in[9];
    const float* be2 = (const float*)d_in[10];

    const int N = in_sizes[5];   // g1 has N elements
    const int E = in_sizes[2];   // norm has E elements
    const int* row = ei;         // edge_index[0] = scatter dst
    const int* col = ei + E;     // edge_index[1] = gather src
    const int nb = (N + 1023) / 1024;

    auto al = [](size_t v) { return (v + 255) & ~(size_t)255; };
    char* p = (char*)d_ws;
    int* off    = (int*)p;   p += al((size_t)(N + 1) * 4);
    int* cur    = (int*)p;   p += al((size_t)N * 4);
    int2* eg    = (int2*)p;  p += al((size_t)E * 8);
    int* bsum   = (int*)p;   p += al((size_t)nb * 4);
    int* boff   = (int*)p;   p += al((size_t)nb * 4);
    u16* Wp1    = (u16*)p;   p += al((size_t)CC * CC * 2);
    u16* Wp2    = (u16*)p;   p += al((size_t)CC * CC * 2);
    u16* Zbuf   = (u16*)p;   p += al((size_t)2 * N * CC * 2);
    u16* A2buf  = (u16*)p;   p += al((size_t)2 * N * CC * 2);

    // CSR by destination (rebuilt every call; deterministic work)
    k_zero_i32<<<(N + 255) / 256, 256, 0, stream>>>(cur, N);
    k_hist<<<(E + 255) / 256, 256, 0, stream>>>(row, cur, E);
    k_scan_a<<<nb, 256, 0, stream>>>(cur, bsum, N);
    k_scan_b<<<1, 64, 0, stream>>>(bsum, boff, off, N, nb);
    k_scan_c<<<nb, 256, 0, stream>>>(cur, boff, off, N);   // also zeroes cur
    k_fill<<<(E + 255) / 256, 256, 0, stream>>>(row, col, nrm, off, cur, eg, E);

    // W -> bf16 fragment-order repack (W2 under the channel permutation pi)
    k_wrepack<<<(2 * CC * CC + 255) / 256, 256, 0, stream>>>(W1, Wp1, W2, Wp2);

    const int gb = (N + 31) / 32;
    const int ga = (N + 3) / 4;
    // K1: GEMM1+BN1+GELU1+GEMM2 -> Z (permuted bf16)
    k_fused_l1<<<gb, 256, 0, stream>>>(x, Wp1, Wp2, b1, g1, be1, Zbuf, N);
    // K2: aggregate + b2 + BN2 + GELU2 -> a2 (permuted bf16)
    k_agg_bn<<<ga, 256, 0, stream>>>(Zbuf, off, eg, b2, g2, be2, A2buf, N);
    // K3: aggregate -> standard f32 out
    k_agg_out<<<ga, 256, 0, stream>>>(A2buf, off, eg, (float*)d_out, N);
}